// Round 2
// baseline (417.861 us; speedup 1.0000x reference)
//
#include <hip/hip_runtime.h>

#define Bz 32
#define Nn 510
#define Dd 64
#define Hh 4
#define HD_ 256
#define Kpad 512
#define ALPHA_ 0.1f
#define LNEPS 1e-5f
#define SLOPE 0.01f
#define NEG_INF -3.0e38f

typedef __attribute__((ext_vector_type(8))) short short8;
typedef __attribute__((ext_vector_type(4))) float floatx4;

__device__ inline float wredsum(float v) {
  #pragma unroll
  for (int off = 32; off; off >>= 1) v += __shfl_xor(v, off, 64);
  return v;
}
__device__ inline float wredmax(float v) {
  #pragma unroll
  for (int off = 32; off; off >>= 1) v = fmaxf(v, __shfl_xor(v, off, 64));
  return v;
}
__device__ inline unsigned short f2bf(float f) {
  unsigned int u = __float_as_uint(f);
  unsigned int r = (u + 0x7fffu + ((u >> 16) & 1u)) >> 16;
  return (unsigned short)r;
}

// K1: xt = x@W; writes xtT bf16 [b][h][d][m(512 padded)] and si/sj (fused).
// Stores go through an LDS transpose tile so global writes are 64B-coalesced.
__global__ __launch_bounds__(256) void k1_xt(const float* __restrict__ x,
                                             const float* __restrict__ W,
                                             const float* __restrict__ attw,
                                             unsigned short* __restrict__ xtT,
                                             float* __restrict__ si,
                                             float* __restrict__ sj) {
  __shared__ float Wl[64][132];
  __shared__ float xr[32][68];
  __shared__ unsigned short st[128 * 65];
  const int t = threadIdx.x;
  const int rt = blockIdx.x;
  const int b = blockIdx.y;
  const int ch = blockIdx.z;
  #pragma unroll
  for (int k = 0; k < 8; k++) {
    int f = t + k * 256;
    int kr = f >> 5;
    int c = (f & 31) * 4;
    float4 v = *(const float4*)&W[kr * HD_ + ch * 128 + c];
    *(float4*)&Wl[kr][c] = v;
  }
  #pragma unroll
  for (int k = 0; k < 2; k++) {
    int f = t + k * 256;
    int r = f >> 4;
    int c = (f & 15) * 4;
    int row = rt * 32 + r;
    float4 v = make_float4(0.f, 0.f, 0.f, 0.f);
    if (row < Nn) v = *(const float4*)&x[(b * Nn + row) * Dd + c];
    *(float4*)&xr[r][c] = v;
  }
  __syncthreads();
  const int tr = t >> 5, tc = t & 31;
  const int rb = tr * 4, c0 = tc * 4;
  float acc[4][4] = {};
  #pragma unroll
  for (int k4 = 0; k4 < 16; k4++) {
    float4 xv[4];
    #pragma unroll
    for (int r = 0; r < 4; r++) xv[r] = *(float4*)&xr[rb + r][k4 * 4];
    #pragma unroll
    for (int kk = 0; kk < 4; kk++) {
      float4 wv = *(float4*)&Wl[k4 * 4 + kk][c0];
      #pragma unroll
      for (int r = 0; r < 4; r++) {
        float xs = (&xv[r].x)[kk];
        acc[r][0] = fmaf(xs, wv.x, acc[r][0]);
        acc[r][1] = fmaf(xs, wv.y, acc[r][1]);
        acc[r][2] = fmaf(xs, wv.z, acc[r][2]);
        acc[r][3] = fmaf(xs, wv.w, acc[r][3]);
      }
    }
  }
  #pragma unroll
  for (int cc = 0; cc < 4; cc++) {
    #pragma unroll
    for (int r = 0; r < 4; r++) {
      st[(c0 + cc) * 65 + rb + r] = f2bf(acc[r][cc]);
    }
  }
  const int colbase = ch * 128 + c0;
  const int h = colbase >> 6;
  const int dd = colbase & 63;
  const int m0r = rt * 32 + rb;
  float w1v[4], w2v[4];
  #pragma unroll
  for (int cc = 0; cc < 4; cc++) {
    w1v[cc] = attw[h * 128 + dd + cc];
    w2v[cc] = attw[h * 128 + 64 + dd + cc];
  }
  #pragma unroll
  for (int r = 0; r < 4; r++) {
    float p1 = acc[r][0] * w1v[0] + acc[r][1] * w1v[1] +
               acc[r][2] * w1v[2] + acc[r][3] * w1v[3];
    float p2 = acc[r][0] * w2v[0] + acc[r][1] * w2v[1] +
               acc[r][2] * w2v[2] + acc[r][3] * w2v[3];
    #pragma unroll
    for (int off = 1; off <= 8; off <<= 1) {
      p1 += __shfl_xor(p1, off, 64);
      p2 += __shfl_xor(p2, off, 64);
    }
    if ((tc & 15) == 0) {
      int row = m0r + r;
      if (row < Nn) {
        si[(b * 4 + h) * Nn + row] = p1;
        sj[(b * 4 + h) * Nn + row] = p2;
      }
    }
  }
  __syncthreads();
  {
    const int rowd = t >> 1;
    const int part = t & 1;
    const int colb2 = ch * 128 + rowd;
    const int h2 = colb2 >> 6;
    const int dd2 = colb2 & 63;
    unsigned short* dst =
        &xtT[((size_t)(b * 4 + h2) * 64 + dd2) * Kpad + rt * 32 + part * 16];
    short8 v0, v1;
    #pragma unroll
    for (int k = 0; k < 8; k++) {
      v0[k] = (short)st[rowd * 65 + part * 16 + k];
      v1[k] = (short)st[rowd * 65 + part * 16 + 8 + k];
    }
    *(short8*)&dst[0] = v0;
    *(short8*)&dst[8] = v1;
  }
}

// K2 fused: attention rows (conv + softmax) -> A (global, mandatory output)
// AND out = 0.25*sum_h A_h @ xt_h via bf16 MFMA on the in-register P rows,
// then fcg/GLU/residual/LN epilogue. k3 is eliminated (saves the 133 MB
// A re-read). P is staged bf16 in LDS *reusing* the dead am_t/cz_t space,
// so LDS stays 52.4 KB -> 3 blocks/CU.
#define PST 2064   // P row stride in shorts: 4*512 + 16 pad (bank spread)
__global__ __launch_bounds__(256) void k2_fused(const float* __restrict__ si,
                                                const float* __restrict__ sj,
                                                const float* __restrict__ causal,
                                                const float* __restrict__ convw,
                                                const float* __restrict__ convb,
                                                const unsigned short* __restrict__ xtT,
                                                const float* __restrict__ x,
                                                const float* __restrict__ fcgw,
                                                const float* __restrict__ fcgb,
                                                const float* __restrict__ lng,
                                                const float* __restrict__ lnb,
                                                float* __restrict__ A,
                                                float* __restrict__ y) {
  __shared__ __align__(16) float smem[10880];   // am_t[5440] + cz_t[5440]
  __shared__ float sjl[4 * 8 * 68];
  __shared__ float sil[4][12];
  float* am_t = smem;
  float* cz_t = smem + 5440;
  const int t = threadIdx.x;
  const int i0 = blockIdx.x * 8;
  const int b = blockIdx.y;
  // pass A: sil, sjl, boundary zeros of am_t/cz_t
  if (t < 40) {
    int h = t / 10, r = t % 10;
    int iq = i0 + r - 1;
    sil[h][r] = (iq >= 0 && iq < Nn) ? si[(b * 4 + h) * Nn + iq] : 0.f;
  }
  if (t >= 64 && t < 224) {
    int q = t - 64;
    int r = q >> 4, rem = q & 15;
    int e = rem >> 1, side = rem & 1;
    int idx = (r * 8 + e) * 68 + side * 65;
    am_t[idx] = 0.f;
    cz_t[idx] = 0.f;
  }
  for (int f = t; f < 2048; f += 256) {
    int h = f >> 9, j = f & 511;
    float v = (j < Nn) ? sj[(b * 4 + h) * Nn + j] : 0.f;
    sjl[(h * 8 + (j & 7)) * 68 + (j >> 3) + 1] = v;
  }
  __syncthreads();
  // pass B: A_mean + causal staging (transposed)
  for (int f = t; f < 5120; f += 256) {
    int r = f >> 9, j = f & 511;
    int iq = i0 + r - 1;
    float am = 0.f, cz = 0.f;
    if (iq >= 0 && iq < Nn && j < Nn) {
      float s = 0.f;
      #pragma unroll
      for (int h = 0; h < 4; h++) {
        float e2 = sil[h][r] + sjl[(h * 8 + (j & 7)) * 68 + (j >> 3) + 1];
        s += (e2 >= 0.f) ? e2 : SLOPE * e2;
      }
      am = 0.25f * s;
      cz = causal[iq * Nn + j];
    }
    int idx = (r * 8 + (j & 7)) * 68 + (j >> 3) + 1;
    am_t[idx] = am;
    cz_t[idx] = cz;
  }
  __syncthreads();
  const int w = t >> 6, L = t & 63;
  const int j0 = L * 8;
  const int h = w;                 // wave w owns head h = w
  const int bh = b * 4 + h;
  float cw[18];
  #pragma unroll
  for (int q = 0; q < 18; q++) cw[q] = convw[h * 18 + q];
  const float cb = convb[h];
  unsigned int pr[8][4];           // P rows packed bf16x2, static-indexed
  #pragma unroll
  for (int il = 0; il < 8; il++) {
    const int i = i0 + il;
    const float sih = sil[h][il + 1];
    float conv[8];
    #pragma unroll
    for (int e = 0; e < 8; e++) conv[e] = cb;
    #pragma unroll
    for (int r3 = 0; r3 < 3; r3++) {
      const float* ba = &am_t[((il + r3) * 8) * 68];
      const float* bc = &cz_t[((il + r3) * 8) * 68];
      float a[10], c[10];
      a[0] = ba[7 * 68 + L];
      c[0] = bc[7 * 68 + L];
      #pragma unroll
      for (int e = 0; e < 8; e++) {
        a[1 + e] = ba[e * 68 + L + 1];
        c[1 + e] = bc[e * 68 + L + 1];
      }
      a[9] = ba[0 * 68 + L + 2];
      c[9] = bc[0 * 68 + L + 2];
      float w0 = cw[r3 * 3], w1 = cw[r3 * 3 + 1], w2 = cw[r3 * 3 + 2];
      float u0 = cw[9 + r3 * 3], u1 = cw[9 + r3 * 3 + 1], u2 = cw[9 + r3 * 3 + 2];
      #pragma unroll
      for (int e = 0; e < 8; e++) {
        float cv = conv[e];
        cv = fmaf(w0, a[e], cv);
        cv = fmaf(w1, a[e + 1], cv);
        cv = fmaf(w2, a[e + 2], cv);
        cv = fmaf(u0, c[e], cv);
        cv = fmaf(u1, c[e + 1], cv);
        cv = fmaf(u2, c[e + 2], cv);
        conv[e] = cv;
      }
    }
    float v[8];
    float mx = NEG_INF;
    #pragma unroll
    for (int e = 0; e < 8; e++) {
      float ee = sih + sjl[(h * 8 + e) * 68 + L + 1];
      float l = (ee >= 0.f) ? ee : SLOPE * ee;
      float val = ALPHA_ * l + (1.0f - ALPHA_) * conv[e];
      v[e] = (j0 + e < Nn) ? val : NEG_INF;
      mx = fmaxf(mx, v[e]);
    }
    mx = wredmax(mx);
    float p[8], s = 0.f;
    #pragma unroll
    for (int e = 0; e < 8; e++) {
      p[e] = __expf(v[e] - mx);
      s += p[e];
    }
    s = wredsum(s);
    const float inv = 1.f / s;
    #pragma unroll
    for (int e = 0; e < 8; e++) p[e] *= inv;
    #pragma unroll
    for (int q = 0; q < 4; q++) {
      pr[il][q] = ((unsigned int)f2bf(p[2 * q + 1]) << 16) | f2bf(p[2 * q]);
    }
    if (i < Nn) {
      float* Ar = &A[((size_t)bh * Nn + i) * Nn + j0];
      *(float4*)&Ar[0] = make_float4(p[0], p[1], p[2], p[3]);
      if (L < 63) {
        *(float4*)&Ar[4] = make_float4(p[4], p[5], p[6], p[7]);
      } else {
        *(float2*)&Ar[4] = make_float2(p[4], p[5]);
      }
    }
  }
  // --- stage P bf16 into LDS (reuses am_t/cz_t space; all reads done) ---
  __syncthreads();
  unsigned short* P = (unsigned short*)smem;   // [8 rows][PST], k = h*512 + j
  #pragma unroll
  for (int il = 0; il < 8; il++) {
    *(uint4*)&P[(size_t)il * PST + h * 512 + j0] =
        make_uint4(pr[il][0], pr[il][1], pr[il][2], pr[il][3]);
  }
  __syncthreads();
  // --- out(8x64) = P(8x2048) @ Xcat(2048x64), one n-tile of 16 d per wave ---
  const int quad = L >> 4, l16 = L & 15;
  const int wc = w * 16;
  floatx4 acc = {0.f, 0.f, 0.f, 0.f};
  #pragma unroll
  for (int h2 = 0; h2 < 4; h2++) {
    const unsigned short* Xh =
        &xtT[((size_t)(b * 4 + h2) * 64 + (wc + l16)) * Kpad];
    #pragma unroll 4
    for (int kt = 0; kt < 16; kt++) {
      short8 af = {0, 0, 0, 0, 0, 0, 0, 0};
      if (l16 < 8)
        af = *(const short8*)&P[l16 * PST + h2 * 512 + kt * 32 + quad * 8];
      short8 bf = *(const short8*)&Xh[kt * 32 + quad * 8];
      acc = __builtin_amdgcn_mfma_f32_16x16x32_bf16(af, bf, acc, 0, 0, 0);
    }
  }
  __syncthreads();
  float* ol = smem + 8256;   // [8][64], placed after P region (byte 33024)
  float* gl = smem + 8768;   // [2][128]
  #pragma unroll
  for (int reg = 0; reg < 4; reg++) {
    int row = quad * 4 + reg;
    if (row < 8) ol[row * 64 + wc + l16] = 0.25f * acc[reg];
  }
  __syncthreads();
  const int kk = t & 127;
  const int rg = t >> 7;
  for (int it = 0; it < 4; it++) {
    const int r = it * 2 + rg;
    const int row = i0 + r;
    float g = fcgb[kk];
    #pragma unroll
    for (int d = 0; d < 64; d++) g = fmaf(ol[r * 64 + d], fcgw[d * 128 + kk], g);
    gl[rg * 128 + kk] = g;
    __syncthreads();
    if (kk < 64 && row < Nn) {
      float a = gl[rg * 128 + kk];
      float bb = gl[rg * 128 + kk + 64];
      float glu = a / (1.f + __expf(-bb));
      float yv = glu + x[(b * Nn + row) * Dd + kk];
      float mu = wredsum(yv) * (1.f / 64.f);
      float dv = yv - mu;
      float var = wredsum(dv * dv) * (1.f / 64.f);
      float o = dv * rsqrtf(var + LNEPS) * lng[kk] + lnb[kk];
      y[(b * Nn + row) * Dd + kk] = o;
    }
    __syncthreads();
  }
}

extern "C" void kernel_launch(void* const* d_in, const int* in_sizes, int n_in,
                              void* d_out, int out_size, void* d_ws, size_t ws_size,
                              hipStream_t stream) {
  const float* x      = (const float*)d_in[0];
  const float* causal = (const float*)d_in[1];
  const float* W      = (const float*)d_in[2];
  const float* attw   = (const float*)d_in[3];
  const float* convw  = (const float*)d_in[4];
  const float* convb  = (const float*)d_in[5];
  const float* fcgw   = (const float*)d_in[6];
  const float* fcgb   = (const float*)d_in[7];
  const float* lng    = (const float*)d_in[8];
  const float* lnb    = (const float*)d_in[9];

  float* ws = (float*)d_ws;
  float* si = ws;                                  // 65,280 floats
  float* sj = si + (size_t)Bz * Hh * Nn;           // 65,280 floats (+16 pad)
  unsigned short* xtT = (unsigned short*)(sj + (size_t)Bz * Hh * Nn + 16);

  float* yout = (float*)d_out;                     // 32*510*64
  float* Aout = yout + (size_t)Bz * Nn * Dd;       // 32*4*510*510

  k1_xt   <<<dim3(16, Bz, 2), 256, 0, stream>>>(x, W, attw, xtT, si, sj);
  k2_fused<<<dim3(64, Bz), 256, 0, stream>>>(si, sj, causal, convw, convb,
                                             xtT, x, fcgw, fcgb, lng, lnb,
                                             Aout, yout);
}

// Round 3
// 293.145 us; speedup vs baseline: 1.4254x; 1.4254x over previous
//
#include <hip/hip_runtime.h>

#define Bz 32
#define Nn 510
#define Dd 64
#define Hh 4
#define HD_ 256
#define Kpad 512
#define ALPHA_ 0.1f
#define LNEPS 1e-5f
#define SLOPE 0.01f
#define NEG_INF -3.0e38f

typedef __attribute__((ext_vector_type(8))) short short8;
typedef __attribute__((ext_vector_type(4))) float floatx4;

__device__ inline float wredsum(float v) {
  #pragma unroll
  for (int off = 32; off; off >>= 1) v += __shfl_xor(v, off, 64);
  return v;
}
__device__ inline float wredmax(float v) {
  #pragma unroll
  for (int off = 32; off; off >>= 1) v = fmaxf(v, __shfl_xor(v, off, 64));
  return v;
}
__device__ inline unsigned short f2bf(float f) {
  unsigned int u = __float_as_uint(f);
  unsigned int r = (u + 0x7fffu + ((u >> 16) & 1u)) >> 16;
  return (unsigned short)r;
}

// K1 v3: one head per block (blockIdx.z = h). LDS 30.3KB -> 5 blocks/CU
// (was 59KB -> 2). Wl fragment reads are broadcast across row-groups and
// 2-way across lanes (conflict-free). Same accumulation order as v2 ->
// xtT/si/sj bit-identical.
__global__ __launch_bounds__(256) void k1_xt(const float* __restrict__ x,
                                             const float* __restrict__ W,
                                             const float* __restrict__ attw,
                                             unsigned short* __restrict__ xtT,
                                             float* __restrict__ si,
                                             float* __restrict__ sj) {
  __shared__ float Wl[64][68];            // [k][d'], 64x64 + pad
  __shared__ float xr[32][68];            // [m_local][k]
  __shared__ unsigned short st[64 * 33];  // [d'][m_local], stride 33
  const int t = threadIdx.x;
  const int rt = blockIdx.x;              // row tile (32 rows)
  const int b = blockIdx.y;
  const int ch = blockIdx.z;              // head 0..3
  #pragma unroll
  for (int k = 0; k < 4; k++) {
    int f = t + k * 256;
    int kr = f >> 4;
    int c = (f & 15) * 4;
    *(float4*)&Wl[kr][c] = *(const float4*)&W[kr * HD_ + ch * 64 + c];
  }
  #pragma unroll
  for (int k = 0; k < 2; k++) {
    int f = t + k * 256;
    int r = f >> 4;
    int c = (f & 15) * 4;
    int row = rt * 32 + r;
    float4 v = make_float4(0.f, 0.f, 0.f, 0.f);
    if (row < Nn) v = *(const float4*)&x[(b * Nn + row) * Dd + c];
    *(float4*)&xr[r][c] = v;
  }
  __syncthreads();
  const int tg = t >> 4;          // row-group 0..15 (2 rows each)
  const int tc = t & 15;          // col-group 0..15 (4 cols each)
  const int rb = tg * 2, c0 = tc * 4;
  float acc[2][4] = {};
  #pragma unroll
  for (int k4 = 0; k4 < 16; k4++) {
    float4 xv0 = *(float4*)&xr[rb][k4 * 4];
    float4 xv1 = *(float4*)&xr[rb + 1][k4 * 4];
    #pragma unroll
    for (int kk = 0; kk < 4; kk++) {
      float4 wv = *(float4*)&Wl[k4 * 4 + kk][c0];
      float xs0 = (&xv0.x)[kk];
      float xs1 = (&xv1.x)[kk];
      acc[0][0] = fmaf(xs0, wv.x, acc[0][0]);
      acc[0][1] = fmaf(xs0, wv.y, acc[0][1]);
      acc[0][2] = fmaf(xs0, wv.z, acc[0][2]);
      acc[0][3] = fmaf(xs0, wv.w, acc[0][3]);
      acc[1][0] = fmaf(xs1, wv.x, acc[1][0]);
      acc[1][1] = fmaf(xs1, wv.y, acc[1][1]);
      acc[1][2] = fmaf(xs1, wv.z, acc[1][2]);
      acc[1][3] = fmaf(xs1, wv.w, acc[1][3]);
    }
  }
  #pragma unroll
  for (int cc = 0; cc < 4; cc++) {
    #pragma unroll
    for (int r = 0; r < 2; r++) {
      st[(c0 + cc) * 33 + rb + r] = f2bf(acc[r][cc]);
    }
  }
  // si/sj: block covers exactly head ch's full d-range.
  float w1v[4], w2v[4];
  #pragma unroll
  for (int cc = 0; cc < 4; cc++) {
    w1v[cc] = attw[ch * 128 + c0 + cc];
    w2v[cc] = attw[ch * 128 + 64 + c0 + cc];
  }
  #pragma unroll
  for (int r = 0; r < 2; r++) {
    float p1 = acc[r][0] * w1v[0] + acc[r][1] * w1v[1] +
               acc[r][2] * w1v[2] + acc[r][3] * w1v[3];
    float p2 = acc[r][0] * w2v[0] + acc[r][1] * w2v[1] +
               acc[r][2] * w2v[2] + acc[r][3] * w2v[3];
    #pragma unroll
    for (int off = 1; off <= 8; off <<= 1) {
      p1 += __shfl_xor(p1, off, 64);
      p2 += __shfl_xor(p2, off, 64);
    }
    if (tc == 0) {
      int row = rt * 32 + rb + r;
      if (row < Nn) {
        si[(b * 4 + ch) * Nn + row] = p1;
        sj[(b * 4 + ch) * Nn + row] = p2;
      }
    }
  }
  __syncthreads();
  // Write-out: thread t (<64) streams one full 64B d-row (coalesced lines).
  if (t < 64) {
    unsigned short* dst = &xtT[((size_t)(b * 4 + ch) * 64 + t) * Kpad + rt * 32];
    #pragma unroll
    for (int q = 0; q < 4; q++) {
      short8 v;
      #pragma unroll
      for (int k = 0; k < 8; k++) v[k] = (short)st[t * 33 + q * 8 + k];
      *(short8*)&dst[q * 8] = v;
    }
  }
}

// K2: verbatim round-1 version (measured 85 us).
__global__ __launch_bounds__(256) void k2_attn(const float* __restrict__ si,
                                               const float* __restrict__ sj,
                                               const float* __restrict__ causal,
                                               const float* __restrict__ convw,
                                               const float* __restrict__ convb,
                                               float* __restrict__ A) {
  __shared__ float am_t[10 * 8 * 68];
  __shared__ float cz_t[10 * 8 * 68];
  __shared__ float sjl[4 * 8 * 68];
  __shared__ float sil[4][12];
  const int t = threadIdx.x;
  const int i0 = blockIdx.x * 8;
  const int b = blockIdx.y;
  if (t < 40) {
    int h = t / 10, r = t % 10;
    int iq = i0 + r - 1;
    sil[h][r] = (iq >= 0 && iq < Nn) ? si[(b * 4 + h) * Nn + iq] : 0.f;
  }
  if (t >= 64 && t < 224) {
    int q = t - 64;
    int r = q >> 4, rem = q & 15;
    int e = rem >> 1, side = rem & 1;
    int idx = (r * 8 + e) * 68 + side * 65;
    am_t[idx] = 0.f;
    cz_t[idx] = 0.f;
  }
  for (int f = t; f < 2048; f += 256) {
    int h = f >> 9, j = f & 511;
    float v = (j < Nn) ? sj[(b * 4 + h) * Nn + j] : 0.f;
    sjl[(h * 8 + (j & 7)) * 68 + (j >> 3) + 1] = v;
  }
  __syncthreads();
  for (int f = t; f < 5120; f += 256) {
    int r = f >> 9, j = f & 511;
    int iq = i0 + r - 1;
    float am = 0.f, cz = 0.f;
    if (iq >= 0 && iq < Nn && j < Nn) {
      float s = 0.f;
      #pragma unroll
      for (int h = 0; h < 4; h++) {
        float e2 = sil[h][r] + sjl[(h * 8 + (j & 7)) * 68 + (j >> 3) + 1];
        s += (e2 >= 0.f) ? e2 : SLOPE * e2;
      }
      am = 0.25f * s;
      cz = causal[iq * Nn + j];
    }
    int idx = (r * 8 + (j & 7)) * 68 + (j >> 3) + 1;
    am_t[idx] = am;
    cz_t[idx] = cz;
  }
  __syncthreads();
  const int w = t >> 6, L = t & 63;
  const int j0 = L * 8;
  for (int pp = w; pp < 32; pp += 4) {
    const int il = pp >> 2, h = pp & 3;
    const int i = i0 + il;
    if (i >= Nn) continue;
    const int bh = b * 4 + h;
    const float sih = sil[h][il + 1];
    float cw[18];
    #pragma unroll
    for (int q = 0; q < 18; q++) cw[q] = convw[h * 18 + q];
    const float cb = convb[h];
    float conv[8];
    #pragma unroll
    for (int e = 0; e < 8; e++) conv[e] = cb;
    #pragma unroll
    for (int r3 = 0; r3 < 3; r3++) {
      const float* ba = &am_t[((il + r3) * 8) * 68];
      const float* bc = &cz_t[((il + r3) * 8) * 68];
      float a[10], c[10];
      a[0] = ba[7 * 68 + L];
      c[0] = bc[7 * 68 + L];
      #pragma unroll
      for (int e = 0; e < 8; e++) {
        a[1 + e] = ba[e * 68 + L + 1];
        c[1 + e] = bc[e * 68 + L + 1];
      }
      a[9] = ba[0 * 68 + L + 2];
      c[9] = bc[0 * 68 + L + 2];
      float w0 = cw[r3 * 3], w1 = cw[r3 * 3 + 1], w2 = cw[r3 * 3 + 2];
      float u0 = cw[9 + r3 * 3], u1 = cw[9 + r3 * 3 + 1], u2 = cw[9 + r3 * 3 + 2];
      #pragma unroll
      for (int e = 0; e < 8; e++) {
        float cv = conv[e];
        cv = fmaf(w0, a[e], cv);
        cv = fmaf(w1, a[e + 1], cv);
        cv = fmaf(w2, a[e + 2], cv);
        cv = fmaf(u0, c[e], cv);
        cv = fmaf(u1, c[e + 1], cv);
        cv = fmaf(u2, c[e + 2], cv);
        conv[e] = cv;
      }
    }
    float v[8];
    float mx = NEG_INF;
    #pragma unroll
    for (int e = 0; e < 8; e++) {
      float ee = sih + sjl[(h * 8 + e) * 68 + L + 1];
      float l = (ee >= 0.f) ? ee : SLOPE * ee;
      float val = ALPHA_ * l + (1.0f - ALPHA_) * conv[e];
      v[e] = (j0 + e < Nn) ? val : NEG_INF;
      mx = fmaxf(mx, v[e]);
    }
    mx = wredmax(mx);
    float p[8], s = 0.f;
    #pragma unroll
    for (int e = 0; e < 8; e++) {
      p[e] = __expf(v[e] - mx);
      s += p[e];
    }
    s = wredsum(s);
    const float inv = 1.f / s;
    #pragma unroll
    for (int e = 0; e < 8; e++) p[e] *= inv;
    float* Ar = &A[((size_t)bh * Nn + i) * Nn + j0];
    *(float4*)&Ar[0] = make_float4(p[0], p[1], p[2], p[3]);
    if (L < 63) {
      *(float4*)&Ar[4] = make_float4(p[4], p[5], p[6], p[7]);
    } else {
      *(float2*)&Ar[4] = make_float2(p[4], p[5]);
    }
  }
}

// K3 v2: direct-load MFMA, no LDS staging, no barriers in the K-loop.
// A-fragment: lane(l16,quad) holds A[n0+l16][m0+quad*8 .. +7] (fp32->bf16,
// float2 loads: row stride 2040B is 8B-aligned). X-fragment: 16B-aligned
// short8 straight from xtT. Same k-accumulation order as old k3 -> y
// bit-identical. Epilogue unchanged.
__global__ __launch_bounds__(256) void k3_out(const float* __restrict__ A,
                                              const unsigned short* __restrict__ xtT,
                                              const float* __restrict__ x,
                                              const float* __restrict__ fcgw,
                                              const float* __restrict__ fcgb,
                                              const float* __restrict__ lng,
                                              const float* __restrict__ lnb,
                                              float* __restrict__ y) {
  __shared__ float ol[16][64];
  __shared__ float gl[2][128];
  const int t = threadIdx.x;
  const int n0 = blockIdx.x * 16;
  const int b = blockIdx.y;
  const int w = t >> 6, L = t & 63;
  const int quad = L >> 4, l16 = L & 15;
  const int wc = w * 16;
  const int arow = (n0 + l16 < Nn) ? (n0 + l16) : (Nn - 1);  // clamp; rows>=Nn discarded
  floatx4 acc = {0.f, 0.f, 0.f, 0.f};
  for (int h = 0; h < 4; h++) {
    const float* Ar = &A[((size_t)(b * 4 + h) * Nn + arow) * Nn];
    const unsigned short* Xr = &xtT[((size_t)(b * 4 + h) * 64 + wc + l16) * Kpad];
    #pragma unroll 4
    for (int kt = 0; kt < 16; kt++) {
      const int m = kt * 32 + quad * 8;
      float av[8];
      if (m != 504) {
        #pragma unroll
        for (int q = 0; q < 4; q++) {
          float2 v = *(const float2*)&Ar[m + q * 2];
          av[q * 2] = v.x;
          av[q * 2 + 1] = v.y;
        }
      } else {
        // tail: j=510,511 are OOB of the A row; X there is zero anyway.
        #pragma unroll
        for (int q = 0; q < 3; q++) {
          float2 v = *(const float2*)&Ar[m + q * 2];
          av[q * 2] = v.x;
          av[q * 2 + 1] = v.y;
        }
        av[6] = 0.f;
        av[7] = 0.f;
      }
      short8 af;
      #pragma unroll
      for (int e = 0; e < 8; e++) af[e] = (short)f2bf(av[e]);
      short8 bf = *(const short8*)&Xr[m];
      acc = __builtin_amdgcn_mfma_f32_16x16x32_bf16(af, bf, acc, 0, 0, 0);
    }
  }
  #pragma unroll
  for (int reg = 0; reg < 4; reg++) {
    ol[quad * 4 + reg][wc + l16] = 0.25f * acc[reg];
  }
  __syncthreads();
  const int kk = t & 127;
  const int rg = t >> 7;
  for (int it = 0; it < 8; it++) {
    const int r = it * 2 + rg;
    const int row = n0 + r;
    float g = fcgb[kk];
    #pragma unroll
    for (int d = 0; d < 64; d++) g = fmaf(ol[r][d], fcgw[d * 128 + kk], g);
    gl[rg][kk] = g;
    __syncthreads();
    if (kk < 64 && row < Nn) {
      float a = gl[rg][kk];
      float bb = gl[rg][kk + 64];
      float glu = a / (1.f + __expf(-bb));
      float yv = glu + x[(b * Nn + row) * Dd + kk];
      float mu = wredsum(yv) * (1.f / 64.f);
      float dv = yv - mu;
      float var = wredsum(dv * dv) * (1.f / 64.f);
      float o = dv * rsqrtf(var + LNEPS) * lng[kk] + lnb[kk];
      y[(b * Nn + row) * Dd + kk] = o;
    }
    __syncthreads();
  }
}

extern "C" void kernel_launch(void* const* d_in, const int* in_sizes, int n_in,
                              void* d_out, int out_size, void* d_ws, size_t ws_size,
                              hipStream_t stream) {
  const float* x      = (const float*)d_in[0];
  const float* causal = (const float*)d_in[1];
  const float* W      = (const float*)d_in[2];
  const float* attw   = (const float*)d_in[3];
  const float* convw  = (const float*)d_in[4];
  const float* convb  = (const float*)d_in[5];
  const float* fcgw   = (const float*)d_in[6];
  const float* fcgb   = (const float*)d_in[7];
  const float* lng    = (const float*)d_in[8];
  const float* lnb    = (const float*)d_in[9];

  float* ws = (float*)d_ws;
  float* si = ws;                                  // 65,280 floats
  float* sj = si + (size_t)Bz * Hh * Nn;           // 65,280 floats (+16 pad)
  unsigned short* xtT = (unsigned short*)(sj + (size_t)Bz * Hh * Nn + 16);

  float* yout = (float*)d_out;                     // 32*510*64
  float* Aout = yout + (size_t)Bz * Nn * Dd;       // 32*4*510*510

  k1_xt  <<<dim3(16, Bz, 4), 256, 0, stream>>>(x, W, attw, xtT, si, sj);
  k2_attn<<<dim3(64, Bz), 256, 0, stream>>>(si, sj, causal, convw, convb, Aout);
  k3_out <<<dim3(32, Bz), 256, 0, stream>>>(Aout, xtT, x, fcgw, fcgb, lng, lnb, yout);
}

// Round 4
// 274.004 us; speedup vs baseline: 1.5250x; 1.0699x over previous
//
#include <hip/hip_runtime.h>

#define Bz 32
#define Nn 510
#define Dd 64
#define Hh 4
#define HD_ 256
#define Kpad 512
#define ALPHA_ 0.1f
#define LNEPS 1e-5f
#define SLOPE 0.01f
#define NEG_INF -3.0e38f

typedef __attribute__((ext_vector_type(8))) short short8;
typedef __attribute__((ext_vector_type(4))) float floatx4;

__device__ inline float wredsum(float v) {
  #pragma unroll
  for (int off = 32; off; off >>= 1) v += __shfl_xor(v, off, 64);
  return v;
}
__device__ inline float wredmax(float v) {
  #pragma unroll
  for (int off = 32; off; off >>= 1) v = fmaxf(v, __shfl_xor(v, off, 64));
  return v;
}
__device__ inline unsigned short f2bf(float f) {
  unsigned int u = __float_as_uint(f);
  unsigned int r = (u + 0x7fffu + ((u >> 16) & 1u)) >> 16;
  return (unsigned short)r;
}

// K1 v3: one head per block (blockIdx.z = h). LDS 30.3KB -> 5 blocks/CU.
// Wl fragment reads broadcast/2-way (conflict-free). Same accumulation
// order as v2 -> xtT/si/sj bit-identical.
__global__ __launch_bounds__(256) void k1_xt(const float* __restrict__ x,
                                             const float* __restrict__ W,
                                             const float* __restrict__ attw,
                                             unsigned short* __restrict__ xtT,
                                             float* __restrict__ si,
                                             float* __restrict__ sj) {
  __shared__ float Wl[64][68];
  __shared__ float xr[32][68];
  __shared__ unsigned short st[64 * 33];
  const int t = threadIdx.x;
  const int rt = blockIdx.x;
  const int b = blockIdx.y;
  const int ch = blockIdx.z;
  #pragma unroll
  for (int k = 0; k < 4; k++) {
    int f = t + k * 256;
    int kr = f >> 4;
    int c = (f & 15) * 4;
    *(float4*)&Wl[kr][c] = *(const float4*)&W[kr * HD_ + ch * 64 + c];
  }
  #pragma unroll
  for (int k = 0; k < 2; k++) {
    int f = t + k * 256;
    int r = f >> 4;
    int c = (f & 15) * 4;
    int row = rt * 32 + r;
    float4 v = make_float4(0.f, 0.f, 0.f, 0.f);
    if (row < Nn) v = *(const float4*)&x[(b * Nn + row) * Dd + c];
    *(float4*)&xr[r][c] = v;
  }
  __syncthreads();
  const int tg = t >> 4;
  const int tc = t & 15;
  const int rb = tg * 2, c0 = tc * 4;
  float acc[2][4] = {};
  #pragma unroll
  for (int k4 = 0; k4 < 16; k4++) {
    float4 xv0 = *(float4*)&xr[rb][k4 * 4];
    float4 xv1 = *(float4*)&xr[rb + 1][k4 * 4];
    #pragma unroll
    for (int kk = 0; kk < 4; kk++) {
      float4 wv = *(float4*)&Wl[k4 * 4 + kk][c0];
      float xs0 = (&xv0.x)[kk];
      float xs1 = (&xv1.x)[kk];
      acc[0][0] = fmaf(xs0, wv.x, acc[0][0]);
      acc[0][1] = fmaf(xs0, wv.y, acc[0][1]);
      acc[0][2] = fmaf(xs0, wv.z, acc[0][2]);
      acc[0][3] = fmaf(xs0, wv.w, acc[0][3]);
      acc[1][0] = fmaf(xs1, wv.x, acc[1][0]);
      acc[1][1] = fmaf(xs1, wv.y, acc[1][1]);
      acc[1][2] = fmaf(xs1, wv.z, acc[1][2]);
      acc[1][3] = fmaf(xs1, wv.w, acc[1][3]);
    }
  }
  #pragma unroll
  for (int cc = 0; cc < 4; cc++) {
    #pragma unroll
    for (int r = 0; r < 2; r++) {
      st[(c0 + cc) * 33 + rb + r] = f2bf(acc[r][cc]);
    }
  }
  float w1v[4], w2v[4];
  #pragma unroll
  for (int cc = 0; cc < 4; cc++) {
    w1v[cc] = attw[ch * 128 + c0 + cc];
    w2v[cc] = attw[ch * 128 + 64 + c0 + cc];
  }
  #pragma unroll
  for (int r = 0; r < 2; r++) {
    float p1 = acc[r][0] * w1v[0] + acc[r][1] * w1v[1] +
               acc[r][2] * w1v[2] + acc[r][3] * w1v[3];
    float p2 = acc[r][0] * w2v[0] + acc[r][1] * w2v[1] +
               acc[r][2] * w2v[2] + acc[r][3] * w2v[3];
    #pragma unroll
    for (int off = 1; off <= 8; off <<= 1) {
      p1 += __shfl_xor(p1, off, 64);
      p2 += __shfl_xor(p2, off, 64);
    }
    if (tc == 0) {
      int row = rt * 32 + rb + r;
      if (row < Nn) {
        si[(b * 4 + ch) * Nn + row] = p1;
        sj[(b * 4 + ch) * Nn + row] = p2;
      }
    }
  }
  __syncthreads();
  if (t < 64) {
    unsigned short* dst = &xtT[((size_t)(b * 4 + ch) * 64 + t) * Kpad + rt * 32];
    #pragma unroll
    for (int q = 0; q < 4; q++) {
      short8 v;
      #pragma unroll
      for (int k = 0; k < 8; k++) v[k] = (short)st[t * 33 + q * 8 + k];
      *(short8*)&dst[q * 8] = v;
    }
  }
}

// K2: verbatim round-1 version (measured 85 us).
__global__ __launch_bounds__(256) void k2_attn(const float* __restrict__ si,
                                               const float* __restrict__ sj,
                                               const float* __restrict__ causal,
                                               const float* __restrict__ convw,
                                               const float* __restrict__ convb,
                                               float* __restrict__ A) {
  __shared__ float am_t[10 * 8 * 68];
  __shared__ float cz_t[10 * 8 * 68];
  __shared__ float sjl[4 * 8 * 68];
  __shared__ float sil[4][12];
  const int t = threadIdx.x;
  const int i0 = blockIdx.x * 8;
  const int b = blockIdx.y;
  if (t < 40) {
    int h = t / 10, r = t % 10;
    int iq = i0 + r - 1;
    sil[h][r] = (iq >= 0 && iq < Nn) ? si[(b * 4 + h) * Nn + iq] : 0.f;
  }
  if (t >= 64 && t < 224) {
    int q = t - 64;
    int r = q >> 4, rem = q & 15;
    int e = rem >> 1, side = rem & 1;
    int idx = (r * 8 + e) * 68 + side * 65;
    am_t[idx] = 0.f;
    cz_t[idx] = 0.f;
  }
  for (int f = t; f < 2048; f += 256) {
    int h = f >> 9, j = f & 511;
    float v = (j < Nn) ? sj[(b * 4 + h) * Nn + j] : 0.f;
    sjl[(h * 8 + (j & 7)) * 68 + (j >> 3) + 1] = v;
  }
  __syncthreads();
  for (int f = t; f < 5120; f += 256) {
    int r = f >> 9, j = f & 511;
    int iq = i0 + r - 1;
    float am = 0.f, cz = 0.f;
    if (iq >= 0 && iq < Nn && j < Nn) {
      float s = 0.f;
      #pragma unroll
      for (int h = 0; h < 4; h++) {
        float e2 = sil[h][r] + sjl[(h * 8 + (j & 7)) * 68 + (j >> 3) + 1];
        s += (e2 >= 0.f) ? e2 : SLOPE * e2;
      }
      am = 0.25f * s;
      cz = causal[iq * Nn + j];
    }
    int idx = (r * 8 + (j & 7)) * 68 + (j >> 3) + 1;
    am_t[idx] = am;
    cz_t[idx] = cz;
  }
  __syncthreads();
  const int w = t >> 6, L = t & 63;
  const int j0 = L * 8;
  for (int pp = w; pp < 32; pp += 4) {
    const int il = pp >> 2, h = pp & 3;
    const int i = i0 + il;
    if (i >= Nn) continue;
    const int bh = b * 4 + h;
    const float sih = sil[h][il + 1];
    float cw[18];
    #pragma unroll
    for (int q = 0; q < 18; q++) cw[q] = convw[h * 18 + q];
    const float cb = convb[h];
    float conv[8];
    #pragma unroll
    for (int e = 0; e < 8; e++) conv[e] = cb;
    #pragma unroll
    for (int r3 = 0; r3 < 3; r3++) {
      const float* ba = &am_t[((il + r3) * 8) * 68];
      const float* bc = &cz_t[((il + r3) * 8) * 68];
      float a[10], c[10];
      a[0] = ba[7 * 68 + L];
      c[0] = bc[7 * 68 + L];
      #pragma unroll
      for (int e = 0; e < 8; e++) {
        a[1 + e] = ba[e * 68 + L + 1];
        c[1 + e] = bc[e * 68 + L + 1];
      }
      a[9] = ba[0 * 68 + L + 2];
      c[9] = bc[0 * 68 + L + 2];
      float w0 = cw[r3 * 3], w1 = cw[r3 * 3 + 1], w2 = cw[r3 * 3 + 2];
      float u0 = cw[9 + r3 * 3], u1 = cw[9 + r3 * 3 + 1], u2 = cw[9 + r3 * 3 + 2];
      #pragma unroll
      for (int e = 0; e < 8; e++) {
        float cv = conv[e];
        cv = fmaf(w0, a[e], cv);
        cv = fmaf(w1, a[e + 1], cv);
        cv = fmaf(w2, a[e + 2], cv);
        cv = fmaf(u0, c[e], cv);
        cv = fmaf(u1, c[e + 1], cv);
        cv = fmaf(u2, c[e + 2], cv);
        conv[e] = cv;
      }
    }
    float v[8];
    float mx = NEG_INF;
    #pragma unroll
    for (int e = 0; e < 8; e++) {
      float ee = sih + sjl[(h * 8 + e) * 68 + L + 1];
      float l = (ee >= 0.f) ? ee : SLOPE * ee;
      float val = ALPHA_ * l + (1.0f - ALPHA_) * conv[e];
      v[e] = (j0 + e < Nn) ? val : NEG_INF;
      mx = fmaxf(mx, v[e]);
    }
    mx = wredmax(mx);
    float p[8], s = 0.f;
    #pragma unroll
    for (int e = 0; e < 8; e++) {
      p[e] = __expf(v[e] - mx);
      s += p[e];
    }
    s = wredsum(s);
    const float inv = 1.f / s;
    #pragma unroll
    for (int e = 0; e < 8; e++) p[e] *= inv;
    float* Ar = &A[((size_t)bh * Nn + i) * Nn + j0];
    *(float4*)&Ar[0] = make_float4(p[0], p[1], p[2], p[3]);
    if (L < 63) {
      *(float4*)&Ar[4] = make_float4(p[4], p[5], p[6], p[7]);
    } else {
      *(float2*)&Ar[4] = make_float2(p[4], p[5]);
    }
  }
}

// K3 v3: A staged once per block via double-buffered LDS (wave-shared
// operand), X read directly from global (per-wave-exclusive rows, 16B
// aligned). Xsub staging eliminated; one barrier per 64-m phase (32 total).
// LDS 9.7KB -> ~8 blocks/CU. Same k-accumulation order as v1 -> y
// bit-identical.
__global__ __launch_bounds__(256) void k3_out(const float* __restrict__ A,
                                              const unsigned short* __restrict__ xtT,
                                              const float* __restrict__ x,
                                              const float* __restrict__ fcgw,
                                              const float* __restrict__ fcgb,
                                              const float* __restrict__ lng,
                                              const float* __restrict__ lnb,
                                              float* __restrict__ y) {
  __shared__ unsigned short Asub[2][16 * 72];
  __shared__ float ol[16][64];
  __shared__ float gl[2][128];
  const int t = threadIdx.x;
  const int n0 = blockIdx.x * 16;
  const int b = blockIdx.y;
  const int w = t >> 6, L = t & 63;
  const int quad = L >> 4, l16 = L & 15;
  const int wc = w * 16;
  const int ar = t >> 4;          // staging row 0..15
  const int amc = (t & 15) * 4;   // staging m-offset (4 floats)
  const int nrow = n0 + ar;
  floatx4 acc = {0.f, 0.f, 0.f, 0.f};

  // phase p = h*8 + kt, m0 = (p&7)*64. Stage phase into Asub[p&1].
  auto stage = [&](int p) {
    const int h = p >> 3;
    const int m = (p & 7) * 64 + amc;
    float av[4] = {0.f, 0.f, 0.f, 0.f};
    if (nrow < Nn) {
      const float* src = &A[((size_t)(b * 4 + h) * Nn + nrow) * Nn + m];
      if (m + 3 < Nn) {
        float2 v0 = *(const float2*)&src[0];
        float2 v1 = *(const float2*)&src[2];
        av[0] = v0.x; av[1] = v0.y; av[2] = v1.x; av[3] = v1.y;
      } else {
        int lim = Nn - m;
        #pragma unroll
        for (int q = 0; q < 4; q++) if (q < lim) av[q] = src[q];
      }
    }
    ushort4 u;
    u.x = f2bf(av[0]); u.y = f2bf(av[1]);
    u.z = f2bf(av[2]); u.w = f2bf(av[3]);
    *(ushort4*)&Asub[p & 1][ar * 72 + amc] = u;
  };

  stage(0);
  __syncthreads();
  #pragma unroll 2
  for (int p = 0; p < 32; p++) {
    if (p + 1 < 32) stage(p + 1);
    const int h = p >> 3;
    const unsigned short* Xr =
        &xtT[((size_t)(b * 4 + h) * 64 + wc + l16) * Kpad + (p & 7) * 64];
    short8 af0 = *(short8*)&Asub[p & 1][l16 * 72 + quad * 8];
    short8 bf0 = *(const short8*)&Xr[quad * 8];
    acc = __builtin_amdgcn_mfma_f32_16x16x32_bf16(af0, bf0, acc, 0, 0, 0);
    short8 af1 = *(short8*)&Asub[p & 1][l16 * 72 + 32 + quad * 8];
    short8 bf1 = *(const short8*)&Xr[32 + quad * 8];
    acc = __builtin_amdgcn_mfma_f32_16x16x32_bf16(af1, bf1, acc, 0, 0, 0);
    __syncthreads();
  }

  #pragma unroll
  for (int reg = 0; reg < 4; reg++) {
    ol[quad * 4 + reg][wc + l16] = 0.25f * acc[reg];
  }
  __syncthreads();
  const int kk = t & 127;
  const int rg = t >> 7;
  for (int it = 0; it < 8; it++) {
    const int r = it * 2 + rg;
    const int row = n0 + r;
    float g = fcgb[kk];
    #pragma unroll
    for (int d = 0; d < 64; d++) g = fmaf(ol[r][d], fcgw[d * 128 + kk], g);
    gl[rg][kk] = g;
    __syncthreads();
    if (kk < 64 && row < Nn) {
      float a = gl[rg][kk];
      float bb = gl[rg][kk + 64];
      float glu = a / (1.f + __expf(-bb));
      float yv = glu + x[(b * Nn + row) * Dd + kk];
      float mu = wredsum(yv) * (1.f / 64.f);
      float dv = yv - mu;
      float var = wredsum(dv * dv) * (1.f / 64.f);
      float o = dv * rsqrtf(var + LNEPS) * lng[kk] + lnb[kk];
      y[(b * Nn + row) * Dd + kk] = o;
    }
    __syncthreads();
  }
}

extern "C" void kernel_launch(void* const* d_in, const int* in_sizes, int n_in,
                              void* d_out, int out_size, void* d_ws, size_t ws_size,
                              hipStream_t stream) {
  const float* x      = (const float*)d_in[0];
  const float* causal = (const float*)d_in[1];
  const float* W      = (const float*)d_in[2];
  const float* attw   = (const float*)d_in[3];
  const float* convw  = (const float*)d_in[4];
  const float* convb  = (const float*)d_in[5];
  const float* fcgw   = (const float*)d_in[6];
  const float* fcgb   = (const float*)d_in[7];
  const float* lng    = (const float*)d_in[8];
  const float* lnb    = (const float*)d_in[9];

  float* ws = (float*)d_ws;
  float* si = ws;                                  // 65,280 floats
  float* sj = si + (size_t)Bz * Hh * Nn;           // 65,280 floats (+16 pad)
  unsigned short* xtT = (unsigned short*)(sj + (size_t)Bz * Hh * Nn + 16);

  float* yout = (float*)d_out;                     // 32*510*64
  float* Aout = yout + (size_t)Bz * Nn * Dd;       // 32*4*510*510

  k1_xt  <<<dim3(16, Bz, 4), 256, 0, stream>>>(x, W, attw, xtT, si, sj);
  k2_attn<<<dim3(64, Bz), 256, 0, stream>>>(si, sj, causal, convw, convb, Aout);
  k3_out <<<dim3(32, Bz), 256, 0, stream>>>(Aout, xtT, x, fcgw, fcgb, lng, lnb, yout);
}

// Round 5
// 260.543 us; speedup vs baseline: 1.6038x; 1.0517x over previous
//
#include <hip/hip_runtime.h>

#define Bz 32
#define Nn 510
#define Dd 64
#define Hh 4
#define HD_ 256
#define Kpad 512
#define ALPHA_ 0.1f
#define LNEPS 1e-5f
#define SLOPE 0.01f
#define NEG_INF -3.0e38f

typedef __attribute__((ext_vector_type(8))) short short8;
typedef __attribute__((ext_vector_type(4))) float floatx4;

__device__ inline float wredsum(float v) {
  #pragma unroll
  for (int off = 32; off; off >>= 1) v += __shfl_xor(v, off, 64);
  return v;
}
__device__ inline float wredmax(float v) {
  #pragma unroll
  for (int off = 32; off; off >>= 1) v = fmaxf(v, __shfl_xor(v, off, 64));
  return v;
}
__device__ inline unsigned short f2bf(float f) {
  unsigned int u = __float_as_uint(f);
  unsigned int r = (u + 0x7fffu + ((u >> 16) & 1u)) >> 16;
  return (unsigned short)r;
}

// K1 v3 (unchanged, verified): one head per block. LDS 30.3KB -> 5 blocks/CU.
__global__ __launch_bounds__(256) void k1_xt(const float* __restrict__ x,
                                             const float* __restrict__ W,
                                             const float* __restrict__ attw,
                                             unsigned short* __restrict__ xtT,
                                             float* __restrict__ si,
                                             float* __restrict__ sj) {
  __shared__ float Wl[64][68];
  __shared__ float xr[32][68];
  __shared__ unsigned short st[64 * 33];
  const int t = threadIdx.x;
  const int rt = blockIdx.x;
  const int b = blockIdx.y;
  const int ch = blockIdx.z;
  #pragma unroll
  for (int k = 0; k < 4; k++) {
    int f = t + k * 256;
    int kr = f >> 4;
    int c = (f & 15) * 4;
    *(float4*)&Wl[kr][c] = *(const float4*)&W[kr * HD_ + ch * 64 + c];
  }
  #pragma unroll
  for (int k = 0; k < 2; k++) {
    int f = t + k * 256;
    int r = f >> 4;
    int c = (f & 15) * 4;
    int row = rt * 32 + r;
    float4 v = make_float4(0.f, 0.f, 0.f, 0.f);
    if (row < Nn) v = *(const float4*)&x[(b * Nn + row) * Dd + c];
    *(float4*)&xr[r][c] = v;
  }
  __syncthreads();
  const int tg = t >> 4;
  const int tc = t & 15;
  const int rb = tg * 2, c0 = tc * 4;
  float acc[2][4] = {};
  #pragma unroll
  for (int k4 = 0; k4 < 16; k4++) {
    float4 xv0 = *(float4*)&xr[rb][k4 * 4];
    float4 xv1 = *(float4*)&xr[rb + 1][k4 * 4];
    #pragma unroll
    for (int kk = 0; kk < 4; kk++) {
      float4 wv = *(float4*)&Wl[k4 * 4 + kk][c0];
      float xs0 = (&xv0.x)[kk];
      float xs1 = (&xv1.x)[kk];
      acc[0][0] = fmaf(xs0, wv.x, acc[0][0]);
      acc[0][1] = fmaf(xs0, wv.y, acc[0][1]);
      acc[0][2] = fmaf(xs0, wv.z, acc[0][2]);
      acc[0][3] = fmaf(xs0, wv.w, acc[0][3]);
      acc[1][0] = fmaf(xs1, wv.x, acc[1][0]);
      acc[1][1] = fmaf(xs1, wv.y, acc[1][1]);
      acc[1][2] = fmaf(xs1, wv.z, acc[1][2]);
      acc[1][3] = fmaf(xs1, wv.w, acc[1][3]);
    }
  }
  #pragma unroll
  for (int cc = 0; cc < 4; cc++) {
    #pragma unroll
    for (int r = 0; r < 2; r++) {
      st[(c0 + cc) * 33 + rb + r] = f2bf(acc[r][cc]);
    }
  }
  float w1v[4], w2v[4];
  #pragma unroll
  for (int cc = 0; cc < 4; cc++) {
    w1v[cc] = attw[ch * 128 + c0 + cc];
    w2v[cc] = attw[ch * 128 + 64 + c0 + cc];
  }
  #pragma unroll
  for (int r = 0; r < 2; r++) {
    float p1 = acc[r][0] * w1v[0] + acc[r][1] * w1v[1] +
               acc[r][2] * w1v[2] + acc[r][3] * w1v[3];
    float p2 = acc[r][0] * w2v[0] + acc[r][1] * w2v[1] +
               acc[r][2] * w2v[2] + acc[r][3] * w2v[3];
    #pragma unroll
    for (int off = 1; off <= 8; off <<= 1) {
      p1 += __shfl_xor(p1, off, 64);
      p2 += __shfl_xor(p2, off, 64);
    }
    if (tc == 0) {
      int row = rt * 32 + rb + r;
      if (row < Nn) {
        si[(b * 4 + ch) * Nn + row] = p1;
        sj[(b * 4 + ch) * Nn + row] = p2;
      }
    }
  }
  __syncthreads();
  if (t < 64) {
    unsigned short* dst = &xtT[((size_t)(b * 4 + ch) * 64 + t) * Kpad + rt * 32];
    #pragma unroll
    for (int q = 0; q < 4; q++) {
      short8 v;
      #pragma unroll
      for (int k = 0; k < 8; k++) v[k] = (short)st[t * 33 + q * 8 + k];
      *(short8*)&dst[q * 8] = v;
    }
  }
}

// K2a (new): causal-channel conv + bias, batch-independent -> computed once.
// ccv[h][i][j(512 padded)] = conv_b[h] + sum_{r3,c3} convw[h][1][r3][c3] *
// causal[i-1+r3][j-1+c3] (zero-padded). 4.2 MB, L3-resident, read by k2.
__global__ __launch_bounds__(256) void k2a_cconv(const float* __restrict__ causal,
                                                 const float* __restrict__ convw,
                                                 const float* __restrict__ convb,
                                                 float* __restrict__ ccv) {
  const int i = blockIdx.x;
  const int t = threadIdx.x;
  #pragma unroll
  for (int qq = 0; qq < 2; qq++) {
    const int j = t + qq * 256;
    float tap[9];
    #pragma unroll
    for (int r3 = 0; r3 < 3; r3++) {
      int ii = i - 1 + r3;
      #pragma unroll
      for (int c3 = 0; c3 < 3; c3++) {
        int jj = j - 1 + c3;
        tap[r3 * 3 + c3] = (ii >= 0 && ii < Nn && jj >= 0 && jj < Nn)
                               ? causal[ii * Nn + jj] : 0.f;
      }
    }
    #pragma unroll
    for (int h = 0; h < 4; h++) {
      float acc = convb[h];
      #pragma unroll
      for (int q = 0; q < 9; q++) acc = fmaf(convw[h * 18 + 9 + q], tap[q], acc);
      ccv[((size_t)h * Nn + i) * 512 + j] = acc;
    }
  }
}

// K2 v2: causal conv hoisted to k2a (halves conv fma, deletes cz_t staging:
// LDS 52.7->30.8KB, 5 blocks/CU). Wave owns 2 i-rows and computes ALL 4
// heads per am-tap load (am LDS reads per wave 240->60).
__global__ __launch_bounds__(256) void k2_attn(const float* __restrict__ si,
                                               const float* __restrict__ sj,
                                               const float* __restrict__ ccv,
                                               const float* __restrict__ convw,
                                               float* __restrict__ A) {
  __shared__ float am_t[10 * 8 * 68];   // [row r][e=j&7][c=(j>>3)+1]
  __shared__ float sjl[4 * 8 * 68];     // [h][e][c]
  __shared__ float sil[4][12];
  __shared__ float cwl[4][9];           // am-channel conv weights
  const int t = threadIdx.x;
  const int i0 = blockIdx.x * 8;
  const int b = blockIdx.y;
  if (t < 36) cwl[t / 9][t % 9] = convw[(t / 9) * 18 + (t % 9)];
  if (t < 40) {
    int h = t / 10, r = t % 10;
    int iq = i0 + r - 1;
    sil[h][r] = (iq >= 0 && iq < Nn) ? si[(b * 4 + h) * Nn + iq] : 0.f;
  }
  if (t >= 64 && t < 224) {
    int q = t - 64;
    int r = q >> 4, rem = q & 15;
    int e = rem >> 1, side = rem & 1;
    am_t[(r * 8 + e) * 68 + side * 65] = 0.f;
  }
  for (int f = t; f < 2048; f += 256) {
    int h = f >> 9, j = f & 511;
    float v = (j < Nn) ? sj[(b * 4 + h) * Nn + j] : 0.f;
    sjl[(h * 8 + (j & 7)) * 68 + (j >> 3) + 1] = v;
  }
  __syncthreads();
  // A_mean staging (transposed), causal load removed.
  for (int f = t; f < 5120; f += 256) {
    int r = f >> 9, j = f & 511;
    int iq = i0 + r - 1;
    float am = 0.f;
    if (iq >= 0 && iq < Nn && j < Nn) {
      float s = 0.f;
      #pragma unroll
      for (int h = 0; h < 4; h++) {
        float e2 = sil[h][r] + sjl[(h * 8 + (j & 7)) * 68 + (j >> 3) + 1];
        s += (e2 >= 0.f) ? e2 : SLOPE * e2;
      }
      am = 0.25f * s;
    }
    am_t[(r * 8 + (j & 7)) * 68 + (j >> 3) + 1] = am;
  }
  __syncthreads();
  const int w = t >> 6, L = t & 63;
  const int j0 = L * 8;
  #pragma unroll
  for (int qq = 0; qq < 2; qq++) {
    const int il = w * 2 + qq;
    const int i = i0 + il;
    if (i >= Nn) continue;
    float conv[4][8];
    #pragma unroll
    for (int h = 0; h < 4; h++) {
      const float* cp = &ccv[((size_t)h * Nn + i) * 512 + j0];
      float4 c0 = *(const float4*)&cp[0];
      float4 c1 = *(const float4*)&cp[4];
      conv[h][0] = c0.x; conv[h][1] = c0.y; conv[h][2] = c0.z; conv[h][3] = c0.w;
      conv[h][4] = c1.x; conv[h][5] = c1.y; conv[h][6] = c1.z; conv[h][7] = c1.w;
    }
    #pragma unroll
    for (int r3 = 0; r3 < 3; r3++) {
      const float* ba = &am_t[((il + r3) * 8) * 68];
      float a[10];
      a[0] = ba[7 * 68 + L];
      #pragma unroll
      for (int e = 0; e < 8; e++) a[1 + e] = ba[e * 68 + L + 1];
      a[9] = ba[0 * 68 + L + 2];
      #pragma unroll
      for (int h = 0; h < 4; h++) {
        float w0 = cwl[h][r3 * 3], w1 = cwl[h][r3 * 3 + 1], w2 = cwl[h][r3 * 3 + 2];
        #pragma unroll
        for (int e = 0; e < 8; e++) {
          float cv = conv[h][e];
          cv = fmaf(w0, a[e], cv);
          cv = fmaf(w1, a[e + 1], cv);
          cv = fmaf(w2, a[e + 2], cv);
          conv[h][e] = cv;
        }
      }
    }
    #pragma unroll
    for (int h = 0; h < 4; h++) {
      const float sih = sil[h][il + 1];
      float v[8];
      float mx = NEG_INF;
      #pragma unroll
      for (int e = 0; e < 8; e++) {
        float ee = sih + sjl[(h * 8 + e) * 68 + L + 1];
        float l = (ee >= 0.f) ? ee : SLOPE * ee;
        float val = ALPHA_ * l + (1.0f - ALPHA_) * conv[h][e];
        v[e] = (j0 + e < Nn) ? val : NEG_INF;
        mx = fmaxf(mx, v[e]);
      }
      mx = wredmax(mx);
      float p[8], s = 0.f;
      #pragma unroll
      for (int e = 0; e < 8; e++) {
        p[e] = __expf(v[e] - mx);
        s += p[e];
      }
      s = wredsum(s);
      const float inv = 1.f / s;
      #pragma unroll
      for (int e = 0; e < 8; e++) p[e] *= inv;
      float* Ar = &A[((size_t)(b * 4 + h) * Nn + i) * Nn + j0];
      *(float4*)&Ar[0] = make_float4(p[0], p[1], p[2], p[3]);
      if (L < 63) {
        *(float4*)&Ar[4] = make_float4(p[4], p[5], p[6], p[7]);
      } else {
        *(float2*)&Ar[4] = make_float2(p[4], p[5]);
      }
    }
  }
}

// K3 v3 (unchanged, verified): A staged via double-buffered LDS, X direct.
__global__ __launch_bounds__(256) void k3_out(const float* __restrict__ A,
                                              const unsigned short* __restrict__ xtT,
                                              const float* __restrict__ x,
                                              const float* __restrict__ fcgw,
                                              const float* __restrict__ fcgb,
                                              const float* __restrict__ lng,
                                              const float* __restrict__ lnb,
                                              float* __restrict__ y) {
  __shared__ unsigned short Asub[2][16 * 72];
  __shared__ float ol[16][64];
  __shared__ float gl[2][128];
  const int t = threadIdx.x;
  const int n0 = blockIdx.x * 16;
  const int b = blockIdx.y;
  const int w = t >> 6, L = t & 63;
  const int quad = L >> 4, l16 = L & 15;
  const int wc = w * 16;
  const int ar = t >> 4;
  const int amc = (t & 15) * 4;
  const int nrow = n0 + ar;
  floatx4 acc = {0.f, 0.f, 0.f, 0.f};

  auto stage = [&](int p) {
    const int h = p >> 3;
    const int m = (p & 7) * 64 + amc;
    float av[4] = {0.f, 0.f, 0.f, 0.f};
    if (nrow < Nn) {
      const float* src = &A[((size_t)(b * 4 + h) * Nn + nrow) * Nn + m];
      if (m + 3 < Nn) {
        float2 v0 = *(const float2*)&src[0];
        float2 v1 = *(const float2*)&src[2];
        av[0] = v0.x; av[1] = v0.y; av[2] = v1.x; av[3] = v1.y;
      } else {
        int lim = Nn - m;
        #pragma unroll
        for (int q = 0; q < 4; q++) if (q < lim) av[q] = src[q];
      }
    }
    ushort4 u;
    u.x = f2bf(av[0]); u.y = f2bf(av[1]);
    u.z = f2bf(av[2]); u.w = f2bf(av[3]);
    *(ushort4*)&Asub[p & 1][ar * 72 + amc] = u;
  };

  stage(0);
  __syncthreads();
  #pragma unroll 2
  for (int p = 0; p < 32; p++) {
    if (p + 1 < 32) stage(p + 1);
    const int h = p >> 3;
    const unsigned short* Xr =
        &xtT[((size_t)(b * 4 + h) * 64 + wc + l16) * Kpad + (p & 7) * 64];
    short8 af0 = *(short8*)&Asub[p & 1][l16 * 72 + quad * 8];
    short8 bf0 = *(const short8*)&Xr[quad * 8];
    acc = __builtin_amdgcn_mfma_f32_16x16x32_bf16(af0, bf0, acc, 0, 0, 0);
    short8 af1 = *(short8*)&Asub[p & 1][l16 * 72 + 32 + quad * 8];
    short8 bf1 = *(const short8*)&Xr[32 + quad * 8];
    acc = __builtin_amdgcn_mfma_f32_16x16x32_bf16(af1, bf1, acc, 0, 0, 0);
    __syncthreads();
  }

  #pragma unroll
  for (int reg = 0; reg < 4; reg++) {
    ol[quad * 4 + reg][wc + l16] = 0.25f * acc[reg];
  }
  __syncthreads();
  const int kk = t & 127;
  const int rg = t >> 7;
  for (int it = 0; it < 8; it++) {
    const int r = it * 2 + rg;
    const int row = n0 + r;
    float g = fcgb[kk];
    #pragma unroll
    for (int d = 0; d < 64; d++) g = fmaf(ol[r][d], fcgw[d * 128 + kk], g);
    gl[rg][kk] = g;
    __syncthreads();
    if (kk < 64 && row < Nn) {
      float a = gl[rg][kk];
      float bb = gl[rg][kk + 64];
      float glu = a / (1.f + __expf(-bb));
      float yv = glu + x[(b * Nn + row) * Dd + kk];
      float mu = wredsum(yv) * (1.f / 64.f);
      float dv = yv - mu;
      float var = wredsum(dv * dv) * (1.f / 64.f);
      float o = dv * rsqrtf(var + LNEPS) * lng[kk] + lnb[kk];
      y[(b * Nn + row) * Dd + kk] = o;
    }
    __syncthreads();
  }
}

extern "C" void kernel_launch(void* const* d_in, const int* in_sizes, int n_in,
                              void* d_out, int out_size, void* d_ws, size_t ws_size,
                              hipStream_t stream) {
  const float* x      = (const float*)d_in[0];
  const float* causal = (const float*)d_in[1];
  const float* W      = (const float*)d_in[2];
  const float* attw   = (const float*)d_in[3];
  const float* convw  = (const float*)d_in[4];
  const float* convb  = (const float*)d_in[5];
  const float* fcgw   = (const float*)d_in[6];
  const float* fcgb   = (const float*)d_in[7];
  const float* lng    = (const float*)d_in[8];
  const float* lnb    = (const float*)d_in[9];

  float* ws = (float*)d_ws;
  float* si = ws;                                  // 65,280 floats
  float* sj = si + (size_t)Bz * Hh * Nn;           // 65,280 floats (+16 pad)
  unsigned short* xtT = (unsigned short*)(sj + (size_t)Bz * Hh * Nn + 16);
  // xtT: 32*4*64*512 shorts = 4,194,304 shorts (8.39 MB)
  float* ccv = (float*)(xtT + (size_t)Bz * Hh * Dd * Kpad);  // 4*510*512 floats

  float* yout = (float*)d_out;                     // 32*510*64
  float* Aout = yout + (size_t)Bz * Nn * Dd;       // 32*4*510*510

  k2a_cconv<<<dim3(Nn), 256, 0, stream>>>(causal, convw, convb, ccv);
  k1_xt  <<<dim3(16, Bz, 4), 256, 0, stream>>>(x, W, attw, xtT, si, sj);
  k2_attn<<<dim3(64, Bz), 256, 0, stream>>>(si, sj, ccv, convw, Aout);
  k3_out <<<dim3(32, Bz), 256, 0, stream>>>(Aout, xtT, x, fcgw, fcgb, lng, lnb, yout);
}